// Round 6
// baseline (604.904 us; speedup 1.0000x reference)
//
#include <hip/hip_runtime.h>

// EvoBinarizedLayer: out[p,b,o] = x@W0 + (1-x)@W1 = x@(W0-W1) + colsum_i(W1)
// x:[32,512,1024] {0,1} fp32; w:[2,32,1024,1024] {0,1} fp32; out fp32. Exact bf16.
//
// R6: three barrier-free streaming kernels. R1-R5 all bound by exposed global
// latency (barrier vmcnt(0) drains, or dependent gather batches). Each kernel
// here is a pure independent-load stream:
//   1) ebl_xconv : x fp32 -> bf16, coalesced copy-shaped.
//   2) ebl_wtrans: w -> dW^T=(W0-W1) bf16 [p][o][k] + colsum(W1) partials.
//      Coalesced 256B dword loads; per-lane k-pack; 16B stores (watch RFO).
//   3) ebl_gemm  : LDS-free, barrier-free, VALU-free GEMM. Both operands
//      k-contiguous bf16 -> fragments are direct dwordx4 loads with constant
//      immediate offsets, fully unrolled, software-pipelined 2 stages.

namespace {

constexpr int PP = 32;
constexpr int BB = 512;
constexpr int II = 1024;
constexpr int OO = 1024;

typedef __attribute__((ext_vector_type(8))) short bf16x8;
typedef __attribute__((ext_vector_type(4))) float f32x4;

// fp32->bf16 truncation (exact for {0,+-1}); packs (lo,hi) into one u32.
__device__ __forceinline__ unsigned pk2(float lo, float hi) {
    return __builtin_amdgcn_perm(__float_as_uint(hi), __float_as_uint(lo),
                                 0x07060302u);
}

// ------------------------------------------------------------ x convert ----
// 512 blocks x 256 thr; grid-stride f32x4 -> bf16x4 (uint2), fully coalesced.
__global__ __launch_bounds__(256, 4) void ebl_xconv(const float* __restrict__ x,
                                                    unsigned short* __restrict__ xbf) {
    const int tid = (int)blockIdx.x * 256 + (int)threadIdx.x;  // 131072 threads
#pragma unroll
    for (int it = 0; it < 32; ++it) {
        const size_t idx = ((size_t)it * 131072 + tid) * 4;
        f32x4 v = *(const f32x4*)(x + idx);
        *(uint2*)(xbf + idx) = make_uint2(pk2(v.x, v.y), pk2(v.z, v.w));
    }
}

// ----------------------------------------------------------- w transform ----
// 4096 wave-tasks (p, o-slice of 64, k-eighth of 128); 1024 blocks x 256 thr.
// Per 32-k tile: 64 coalesced dword loads (256B/instr), subtract, pack to
// 4 x dwordx4 per lane (k-contiguous 64B run at fixed o), colsum accumulate.
// colsum partials -> colsum_part[p][8][1024], summed in the GEMM epilogue.
__global__ __launch_bounds__(256, 4) void ebl_wtrans(const float* __restrict__ w,
                                                     unsigned short* __restrict__ dWT,
                                                     float* __restrict__ csp) {
    const int t  = (int)threadIdx.x;
    const int l  = t & 63;
    const int wv = t >> 6;
    const int id = (int)blockIdx.x * 4 + wv;   // wave-task 0..4095
    const int p   = id >> 7;
    const int o64 = (id >> 3) & 15;
    const int k8  = id & 7;
    const int o   = o64 * 64 + l;

    const float* w0p = w + (size_t)p * II * OO + o;
    const float* w1p = w0p + (size_t)PP * II * OO;
    unsigned short* dp = dWT + ((size_t)p * OO + o) * II;

    float cs = 0.f;

#pragma unroll 1
    for (int it = 0; it < 4; ++it) {
        const int k0 = k8 * 128 + it * 32;
        float q0[32], q1[32];
#pragma unroll
        for (int j = 0; j < 32; ++j) q0[j] = w0p[(size_t)(k0 + j) * OO];
#pragma unroll
        for (int j = 0; j < 32; ++j) q1[j] = w1p[(size_t)(k0 + j) * OO];

        float d[32];
#pragma unroll
        for (int j = 0; j < 32; ++j) {
            d[j] = q0[j] - q1[j];
            cs += q1[j];
        }
#pragma unroll
        for (int c = 0; c < 4; ++c) {
            uint4 st;
            st.x = pk2(d[8 * c + 0], d[8 * c + 1]);
            st.y = pk2(d[8 * c + 2], d[8 * c + 3]);
            st.z = pk2(d[8 * c + 4], d[8 * c + 5]);
            st.w = pk2(d[8 * c + 6], d[8 * c + 7]);
            *(uint4*)(dp + k0 + 8 * c) = st;
        }
    }

    csp[((size_t)p * 8 + k8) * OO + o] = cs;
}

// ------------------------------------------------------------------ GEMM ----
// Barrier-free, LDS-free. Wave tile 64b x 64o; block = 4 waves stacked along b
// (256b x 64o) -> all 4 waves issue IDENTICAL B addresses (L1 dedup); x reuse
// across the 16 o-blocks served by L3 (96MB unique inputs < 256MB).
// K-loop fully unrolled: fragment loads are dwordx4 with constant immediate
// offsets (max 2KB < 4KB limit) -> zero VALU in loop, deep vmem pipeline,
// 2-stage software pipeline. ~125 regs incl 64 acc -> 3 waves/SIMD.
__global__ __launch_bounds__(256, 3) void ebl_gemm(const unsigned short* __restrict__ xbf,
                                                   const unsigned short* __restrict__ dWT,
                                                   const float* __restrict__ csp,
                                                   float* __restrict__ out) {
    const int t  = (int)threadIdx.x;
    const int l  = t & 63;
    const int wv = t >> 6;     // b-slice within block
    const int lq = l >> 4;
    const int ln = l & 15;

    const int p  = (int)blockIdx.z;
    const int o0 = (int)blockIdx.x * 64;
    const int b0 = (int)blockIdx.y * 256 + wv * 64;

    // Per-mt/nt fragment base pointers (row fixed, k advances via immediates).
    const unsigned short* Ab[4];
    const unsigned short* Bb[4];
#pragma unroll
    for (int mt = 0; mt < 4; ++mt)
        Ab[mt] = xbf + ((size_t)p * BB + b0 + mt * 16 + ln) * II + lq * 8;
#pragma unroll
    for (int nt = 0; nt < 4; ++nt)
        Bb[nt] = dWT + ((size_t)p * OO + o0 + nt * 16 + ln) * II + lq * 8;

    f32x4 acc[4][4];
#pragma unroll
    for (int mt = 0; mt < 4; ++mt)
#pragma unroll
        for (int nt = 0; nt < 4; ++nt)
            acc[mt][nt] = (f32x4){0.f, 0.f, 0.f, 0.f};

    bf16x8 aC[4], bC[4], aN[4], bN[4];
#pragma unroll
    for (int i = 0; i < 4; ++i) {
        aC[i] = *(const bf16x8*)(Ab[i]);
        bC[i] = *(const bf16x8*)(Bb[i]);
    }

#pragma unroll
    for (int s = 0; s < 16; ++s) {       // 64 k per iteration, two 32-k stages
        const int o1 = 64 * s + 32;
        const int o2 = 64 * s + 64;      // s==15: prefetch past slice end --
                                         // lands in next ws region, unused, safe
#pragma unroll
        for (int i = 0; i < 4; ++i) {
            aN[i] = *(const bf16x8*)(Ab[i] + o1);
            bN[i] = *(const bf16x8*)(Bb[i] + o1);
        }
#pragma unroll
        for (int mt = 0; mt < 4; ++mt)
#pragma unroll
            for (int nt = 0; nt < 4; ++nt)
                acc[mt][nt] = __builtin_amdgcn_mfma_f32_16x16x32_bf16(
                    aC[mt], bC[nt], acc[mt][nt], 0, 0, 0);
#pragma unroll
        for (int i = 0; i < 4; ++i) {
            aC[i] = *(const bf16x8*)(Ab[i] + o2);
            bC[i] = *(const bf16x8*)(Bb[i] + o2);
        }
#pragma unroll
        for (int mt = 0; mt < 4; ++mt)
#pragma unroll
            for (int nt = 0; nt < 4; ++nt)
                acc[mt][nt] = __builtin_amdgcn_mfma_f32_16x16x32_bf16(
                    aN[mt], bN[nt], acc[mt][nt], 0, 0, 0);
    }

    // colsum for this wave's o-columns: sum the 8 k-partials.
    float cs[4];
#pragma unroll
    for (int nt = 0; nt < 4; ++nt) {
        const int ocol = o0 + nt * 16 + ln;
        float s = 0.f;
#pragma unroll
        for (int g = 0; g < 8; ++g) s += csp[((size_t)p * 8 + g) * OO + ocol];
        cs[nt] = s;
    }

    // Epilogue (R5-verified layout: col=lane&15, row=quad*4+reg).
    float* op = out + ((size_t)p * BB + b0) * OO + o0;
#pragma unroll
    for (int mt = 0; mt < 4; ++mt)
#pragma unroll
        for (int nt = 0; nt < 4; ++nt) {
            const int col = nt * 16 + ln;
#pragma unroll
            for (int r = 0; r < 4; ++r) {
                const int row = mt * 16 + lq * 4 + r;
                op[(size_t)row * OO + col] = acc[mt][nt][r] + cs[nt];
            }
        }
}

}  // namespace

extern "C" void kernel_launch(void* const* d_in, const int* in_sizes, int n_in,
                              void* d_out, int out_size, void* d_ws, size_t ws_size,
                              hipStream_t stream) {
    const float* x = (const float*)d_in[0];
    const float* w = (const float*)d_in[1];
    float* out = (float*)d_out;

    // ws: dWT 64MiB | xbf 32MiB | colsum_part 1MiB  (ws ~1GiB available)
    unsigned short* dWT = (unsigned short*)d_ws;
    unsigned short* xbf = (unsigned short*)((char*)d_ws + (64u << 20));
    float* csp = (float*)((char*)d_ws + (96u << 20));

    ebl_xconv<<<dim3(512), dim3(256), 0, stream>>>(x, xbf);
    ebl_wtrans<<<dim3(1024), dim3(256), 0, stream>>>(w, dWT, csp);
    ebl_gemm<<<dim3(OO / 64, BB / 256, PP), dim3(256), 0, stream>>>(xbf, dWT, csp, out);
}